// Round 9
// baseline (248.464 us; speedup 1.0000x reference)
//
#include <hip/hip_runtime.h>
#include <hip/hip_bf16.h>

// Problem constants (fixed by setup_inputs)
#define NB 16          // molecules
#define NA 384         // atoms per molecule
#define NOFFS 27       // periodic image offsets
#define MAXP 400000
#define CUT 5.5f

#define WPB 8                  // waves per block (512 threads); wave owns one i-row
#define BPM (NA/WPB)           // 48 blocks per molecule
#define NSEGW NA               // 384 segments per molecule (seg == i)
#define NCNT (NB*NOFFS*NSEGW)  // 165888 counters (b,o,i) = 324*512
#define NBLKS (NB*BPM)         // 768 blocks
#define NCHUNK (NCNT/512)      // 324 scan chunks

// ws layout (int32 indices); WS_CNT is scanned IN PLACE (exclusive-in-chunk)
#define WS_CNT   0
#define WS_BMAX  (NCNT)              // per-block max|offset| (768)
#define WS_CSUM  (NCNT + NBLKS)      // per-chunk sums (324)
#define WS_FLAG  (WS_CSUM + NCHUNK)  // barrier init flag
#define WS_BCNT  (WS_FLAG + 1)       // barrier arrive counter
#define WS_GEN   (WS_FLAG + 2)       // barrier generation
#define MAGIC 0x5EC7B477

// IEEE single ops, no FMA contraction (replicate XLA's plain mul/add chain)
__device__ __forceinline__ float f_add(float a, float b){ return __fadd_rn(a,b); }
__device__ __forceinline__ float f_sub(float a, float b){ return __fsub_rn(a,b); }
__device__ __forceinline__ float f_mul(float a, float b){ return __fmul_rn(a,b); }

// 3x3 inverse via adjugate (diagonal cell -> exact diag(1/18), exact 0 elsewhere)
__device__ __forceinline__ void make_inv(const float* cl, float* invc) {
  float a=cl[0], b=cl[1], c=cl[2], d=cl[3], e=cl[4], f=cl[5], g=cl[6], h=cl[7], i=cl[8];
  float A = f_sub(f_mul(e,i), f_mul(f,h));
  float B = f_sub(f_mul(f,g), f_mul(d,i));
  float C = f_sub(f_mul(d,h), f_mul(e,g));
  float det = f_add(f_add(f_mul(a,A), f_mul(b,B)), f_mul(c,C));
  invc[0] = __fdiv_rn(A, det);
  invc[1] = __fdiv_rn(f_sub(f_mul(c,h), f_mul(b,i)), det);
  invc[2] = __fdiv_rn(f_sub(f_mul(b,f), f_mul(c,e)), det);
  invc[3] = __fdiv_rn(B, det);
  invc[4] = __fdiv_rn(f_sub(f_mul(a,i), f_mul(c,g)), det);
  invc[5] = __fdiv_rn(f_sub(f_mul(c,d), f_mul(a,f)), det);
  invc[6] = __fdiv_rn(C, det);
  invc[7] = __fdiv_rn(f_sub(f_mul(b,g), f_mul(a,h)), det);
  invc[8] = __fdiv_rn(f_sub(f_mul(a,e), f_mul(b,d)), det);
}

// Nearest-image select: k = rint(d0/L) in {-1,0,1}; P = -L*k exact; oi = -k.
// Threshold at |d0|~L/2 sits inside the ~7A dead zone between valid bands.
#define SELECT_P(d0, negLd, invLd, P, oi) \
  { const float kk = __builtin_rintf(f_mul(d0, invLd)); \
    P = f_mul(kk, negLd); oi = -(int)kk; }

// Device-scope grid barrier (gen-based, t0-only protocol + block barrier).
__device__ __forceinline__ void gbar(int* ws) {
  __syncthreads();
  if (threadIdx.x == 0) {
    __threadfence();   // publish this block's prior global writes
    const int g = __hip_atomic_load(ws + WS_GEN, __ATOMIC_RELAXED, __HIP_MEMORY_SCOPE_AGENT);
    const int a = __hip_atomic_fetch_add(ws + WS_BCNT, 1, __ATOMIC_ACQ_REL, __HIP_MEMORY_SCOPE_AGENT);
    if (a == NBLKS - 1) {
      __hip_atomic_store(ws + WS_BCNT, 0, __ATOMIC_RELAXED, __HIP_MEMORY_SCOPE_AGENT);
      __hip_atomic_store(ws + WS_GEN, g + 1, __ATOMIC_RELEASE, __HIP_MEMORY_SCOPE_AGENT);
    } else {
      long spins = 0;
      while (__hip_atomic_load(ws + WS_GEN, __ATOMIC_ACQUIRE, __HIP_MEMORY_SCOPE_AGENT) == g) {
        __builtin_amdgcn_s_sleep(4);
        if (++spins > (1L << 26)) break;   // failsafe: fail loudly, never hang
      }
    }
    __threadfence();   // invalidate caches before reading other blocks' data
  }
  __syncthreads();
}

__global__ __launch_bounds__(512, 6) void fused_k(
    const float* __restrict__ coords, const float* __restrict__ cell,
    const int* __restrict__ ira, int* __restrict__ ws,
    float* __restrict__ out)
{
  const int bid = blockIdx.x;
  const int b = bid / BPM;
  const int blkm = bid % BPM;
  __shared__ float wx[NA], wy[NA], wz[NA];
  __shared__ int wox[NA], woy[NA], woz[NA];
  __shared__ float cx[NA], cy[NA], cz[NA];
  __shared__ int ira_s[NA];
  __shared__ float cl[9], invc[9];
  __shared__ int cw[WPB*27];     // phase1: counts; phase3: cursors
  __shared__ int wmax[WPB];
  __shared__ int csh[512], msh[512], cpre_l[NCHUNK];
  const int t = threadIdx.x;
  const int w = t >> 6, lane = t & 63;

  if (t < 9) cl[t] = cell[b*9 + t];
  if (t < WPB*27) cw[t] = 0;
  __syncthreads();
  if (t == 0) {
    // one-time barrier-state init handshake (ws poisoned 0xAA != MAGIC)
    if (bid == 0) {
      if (__hip_atomic_load(ws + WS_FLAG, __ATOMIC_RELAXED, __HIP_MEMORY_SCOPE_AGENT) != MAGIC) {
        __hip_atomic_store(ws + WS_BCNT, 0, __ATOMIC_RELAXED, __HIP_MEMORY_SCOPE_AGENT);
        __hip_atomic_store(ws + WS_GEN, 0, __ATOMIC_RELAXED, __HIP_MEMORY_SCOPE_AGENT);
        __hip_atomic_store(ws + WS_FLAG, MAGIC, __ATOMIC_RELEASE, __HIP_MEMORY_SCOPE_AGENT);
      }
    } else {
      long spins = 0;
      while (__hip_atomic_load(ws + WS_FLAG, __ATOMIC_ACQUIRE, __HIP_MEMORY_SCOPE_AGENT) != MAGIC) {
        __builtin_amdgcn_s_sleep(4);
        if (++spins > (1L << 26)) break;
      }
    }
    make_inv(cl, invc);
  }
  __syncthreads();

  // ---- stage molecule b: wrapped chain + originals + ira ----
  {
    const float3* __restrict__ c3 = (const float3*)(coords + b*NA*3);
    for (int i = t; i < NA; i += 512) {
      const float3 c = c3[i];
      cx[i] = c.x; cy[i] = c.y; cz[i] = c.z;
      ira_s[i] = ira[b*NA + i];
      float p0 = f_add(f_add(f_mul(c.x, invc[0]), f_mul(c.y, invc[3])), f_mul(c.z, invc[6]));
      float p1 = f_add(f_add(f_mul(c.x, invc[1]), f_mul(c.y, invc[4])), f_mul(c.z, invc[7]));
      float p2 = f_add(f_add(f_mul(c.x, invc[2]), f_mul(c.y, invc[5])), f_mul(c.z, invc[8]));
      float fl0 = floorf(p0), fl1 = floorf(p1), fl2 = floorf(p2);
      wox[i] = (int)fl0; woy[i] = (int)fl1; woz[i] = (int)fl2;
      float fr0 = f_sub(p0, fl0), fr1 = f_sub(p1, fl1), fr2 = f_sub(p2, fl2);
      wx[i] = f_add(f_add(f_mul(fr0, cl[0]), f_mul(fr1, cl[3])), f_mul(fr2, cl[6]));
      wy[i] = f_add(f_add(f_mul(fr0, cl[1]), f_mul(fr1, cl[4])), f_mul(fr2, cl[7]));
      wz[i] = f_add(f_add(f_mul(fr0, cl[2]), f_mul(fr1, cl[5])), f_mul(fr2, cl[8]));
    }
  }
  __syncthreads();

  const float nLx = -cl[0], nLy = -cl[4], nLz = -cl[8];
  const float iLx = __frcp_rn(cl[0]), iLy = __frcp_rn(cl[4]), iLz = __frcp_rn(cl[8]);
  const int i = blkm*WPB + w;          // this wave's i-row

  // ---- phase 1: evaluate candidates once; cache packed results ----
  const float wxi = wx[i], wyi = wy[i], wzi = wz[i];
  const int woxi = wox[i], woyi = woy[i], wozi = woz[i];
  int pk[6];
  int mx = 0;
  #pragma unroll
  for (int jb = 0; jb < 6; ++jb) {
    const int j = jb*64 + lane;
    const float d0x = f_sub(wxi, wx[j]);
    const float d0y = f_sub(wyi, wy[j]);
    const float d0z = f_sub(wzi, wz[j]);
    float Px, Py, Pz; int ox, oy, oz;
    SELECT_P(d0x, nLx, iLx, Px, ox);
    SELECT_P(d0y, nLy, iLy, Py, oy);
    SELECT_P(d0z, nLz, iLz, Pz, oz);
    const float dx = f_add(d0x, Px);
    const float dy = f_add(d0y, Py);
    const float dz = f_add(d0z, Pz);
    const float s = f_add(f_add(f_mul(dx,dx), f_mul(dy,dy)), f_mul(dz,dz));
    const float dist = __fsqrt_rn(s);
    const int oidx = 13 + 9*ox + 3*oy + oz;
    const bool valid = (dist < CUT) && (oidx != 13 || i != j);
    const int o0 = ox - (woxi - wox[j]);       // in [-2,2]
    const int o1 = oy - (woyi - woy[j]);
    const int o2 = oz - (wozi - woz[j]);
    pk[jb] = (valid ? 1 : 0) | (oidx << 1) | ((o0+2) << 6) | ((o1+2) << 9) | ((o2+2) << 12);
    if (valid) {
      atomicAdd(&cw[w*27 + oidx], 1);
      int am = abs(o0); am = max(am, abs(o1)); am = max(am, abs(o2));
      mx = max(mx, am);
    }
  }
  #pragma unroll
  for (int d = 32; d > 0; d >>= 1) mx = max(mx, __shfl_down(mx, d));
  if (lane == 0) wmax[w] = mx;
  if (lane < 27) ws[WS_CNT + (b*27 + lane)*NSEGW + i] = cw[w*27 + lane];
  __syncthreads();
  if (t == 0) {
    int m = 0;
    #pragma unroll
    for (int q = 0; q < WPB; ++q) m = max(m, wmax[q]);
    ws[WS_BMAX + bid] = m;
  }

  gbar(ws);

  // ---- phase 2: blocks 0..323 scan one 512-counter chunk in place ----
  if (bid < NCHUNK) {
    const int idx = bid*512 + t;
    const int v = ws[WS_CNT + idx];
    csh[t] = v;
    __syncthreads();
    for (int d = 1; d < 512; d <<= 1) {
      const int add = (t >= d) ? csh[t - d] : 0;
      __syncthreads();
      csh[t] += add;
      __syncthreads();
    }
    ws[WS_CNT + idx] = csh[t] - v;            // exclusive within chunk
    if (t == 511) ws[WS_CSUM + bid] = csh[511];
  }

  gbar(ws);

  // ---- phase 3 prologue: redundant chunk-sum scan + max reduce (LDS) ----
  const int cv = (t < NCHUNK) ? ws[WS_CSUM + t] : 0;
  csh[t] = cv;
  {
    int m = ws[WS_BMAX + t];
    if (t < NBLKS - 512) m = max(m, ws[WS_BMAX + 512 + t]);
    msh[t] = m;
  }
  __syncthreads();
  for (int d = 1; d < 512; d <<= 1) {
    const int add = (t >= d) ? csh[t - d] : 0;
    __syncthreads();
    csh[t] += add;
    __syncthreads();
  }
  for (int d = 256; d > 0; d >>= 1) {
    if (t < d) msh[t] = max(msh[t], msh[t + d]);
    __syncthreads();
  }
  if (t < NCHUNK) cpre_l[t] = csh[t] - cv;    // exclusive chunk prefix
  __syncthreads();
  const int mi = msh[0];
  const int nf = 2*mi + 1;
  int total = csh[511]; if (total > MAXP) total = MAXP;
  __syncthreads();

  // cursors: in-chunk exclusive offset + chunk prefix (cw reused as off_l)
  if (lane < 27) {
    const int idx = (b*27 + lane)*NSEGW + i;
    cw[w*27 + lane] = ws[WS_CNT + idx] + cpre_l[idx >> 9];
  }

  // ---- phase 3: ordered compaction using cached candidate data ----
  const float cxi = cx[i], cyi = cy[i], czi = cz[i];
  const int pfi = ira_s[i];
  #pragma unroll
  for (int jb = 0; jb < 6; ++jb) {
    const int j = jb*64 + lane;
    const int pkv = pk[jb];
    const bool valid = pkv & 1;
    const int oidx = (pkv >> 1) & 31;
    const unsigned long long vm = __ballot(valid);
    unsigned long long same = vm;
    #pragma unroll
    for (int k = 0; k < 5; ++k) {
      const unsigned long long bk = __ballot((oidx >> k) & 1);
      same &= ((oidx >> k) & 1) ? bk : ~bk;
    }
    if (valid) {
      const unsigned long long lower = (1ull << lane) - 1ull;
      const int rank = __popcll(same & lower);
      const int bse = cw[w*27 + oidx];          // broadcast read per group
      if ((same & lower) == 0ull)               // leader advances cursor
        cw[w*27 + oidx] = bse + __popcll(same);
      const int p = bse + rank;
      if (p < MAXP) {
        const int o0 = ((pkv >> 6) & 7) - 2;
        const int o1 = ((pkv >> 9) & 7) - 2;
        const int o2 = ((pkv >> 12) & 7) - 2;
        const float g0 = (float)o0, g1 = (float)o1, g2 = (float)o2;
        const float qx = f_add(f_add(f_mul(g0, cl[0]), f_mul(g1, cl[3])), f_mul(g2, cl[6]));
        const float qy = f_add(f_add(f_mul(g0, cl[1]), f_mul(g1, cl[4])), f_mul(g2, cl[7]));
        const float qz = f_add(f_add(f_mul(g0, cl[2]), f_mul(g1, cl[5])), f_mul(g2, cl[8]));
        const float ax = f_add(f_sub(cxi, cx[j]), qx);
        const float ay = f_add(f_sub(cyi, cy[j]), qy);
        const float az = f_add(f_sub(czi, cz[j]), qz);
        const float s2 = f_add(f_add(f_mul(ax,ax), f_mul(ay,ay)), f_mul(az,az));
        const float dd = __fsqrt_rn(s2);
        out[p]          = dd;
        out[MAXP + p]   = (float)pfi;
        out[2*MAXP + p] = (float)ira_s[j];
        out[3*MAXP + 3*p + 0] = ax;
        out[3*MAXP + 3*p + 1] = ay;
        out[3*MAXP + 3*p + 2] = az;
        out[6*MAXP + 3*p + 0] = g0;
        out[6*MAXP + 3*p + 1] = g1;
        out[6*MAXP + 3*p + 2] = g2;
        out[9*MAXP + p] = (float)((o2+mi) + nf*((o1+mi) + nf*(o0+mi)));
      }
    }
  }

  // Tail fill: slots [total, MAXP) -> zeros except offset_index pad value.
  const float oidx_pad = (float)(mi*(1 + nf + nf*nf));
  const int gtid = bid*512 + t;
  for (int p = total + gtid; p < MAXP; p += NBLKS*512) {
    out[p] = 0.0f;
    out[MAXP + p] = 0.0f;
    out[2*MAXP + p] = 0.0f;
    out[3*MAXP + 3*p + 0] = 0.0f;
    out[3*MAXP + 3*p + 1] = 0.0f;
    out[3*MAXP + 3*p + 2] = 0.0f;
    out[6*MAXP + 3*p + 0] = 0.0f;
    out[6*MAXP + 3*p + 1] = 0.0f;
    out[6*MAXP + 3*p + 2] = 0.0f;
    out[9*MAXP + p] = oidx_pad;
  }
}

extern "C" void kernel_launch(void* const* d_in, const int* in_sizes, int n_in,
                              void* d_out, int out_size, void* d_ws, size_t ws_size,
                              hipStream_t stream) {
  const float* coords = (const float*)d_in[0];   // [16,384,3] f32
  const int*   ira    = (const int*)d_in[3];     // inv_real_atoms [6144]
  const float* cell   = (const float*)d_in[4];   // [16,3,3] f32
  int* ws = (int*)d_ws;
  float* out = (float*)d_out;

  fused_k<<<NBLKS, 512, 0, stream>>>(coords, cell, ira, ws, out);
}

// Round 10
// 31.159 us; speedup vs baseline: 7.9740x; 7.9740x over previous
//
#include <hip/hip_runtime.h>
#include <hip/hip_bf16.h>

// Problem constants (fixed by setup_inputs)
#define NB 16          // molecules
#define NA 384         // atoms per molecule
#define NOFFS 27       // periodic image offsets
#define MAXP 400000
#define CUT 5.5f

#define WPB 8                  // waves per block (512 threads); wave owns one i-row
#define BPM (NA/WPB)           // 48 blocks per molecule
#define NBLKS (NB*BPM)         // 768 blocks
#define NPB (NB*NOFFS*BPM)     // 20736 per-(b,o,block) partial counts
#define NWC (NBLKS*216)        // per-(block,o,wave) counts

// ws layout (int32 indices)
#define WS_PB    0             // PB[(b*27+o)*48 + blkm]
#define WS_WCNT  (NPB)         // WCNT[bid*216 + o*8 + w]
#define WS_BMAX  (NPB + NWC)   // per-block max|offset| (768)

// IEEE single ops, no FMA contraction (replicate XLA's plain mul/add chain)
__device__ __forceinline__ float f_add(float a, float b){ return __fadd_rn(a,b); }
__device__ __forceinline__ float f_sub(float a, float b){ return __fsub_rn(a,b); }
__device__ __forceinline__ float f_mul(float a, float b){ return __fmul_rn(a,b); }

// 3x3 inverse via adjugate (diagonal cell -> exact diag(1/18), exact 0 elsewhere)
__device__ __forceinline__ void make_inv(const float* cl, float* invc) {
  float a=cl[0], b=cl[1], c=cl[2], d=cl[3], e=cl[4], f=cl[5], g=cl[6], h=cl[7], i=cl[8];
  float A = f_sub(f_mul(e,i), f_mul(f,h));
  float B = f_sub(f_mul(f,g), f_mul(d,i));
  float C = f_sub(f_mul(d,h), f_mul(e,g));
  float det = f_add(f_add(f_mul(a,A), f_mul(b,B)), f_mul(c,C));
  invc[0] = __fdiv_rn(A, det);
  invc[1] = __fdiv_rn(f_sub(f_mul(c,h), f_mul(b,i)), det);
  invc[2] = __fdiv_rn(f_sub(f_mul(b,f), f_mul(c,e)), det);
  invc[3] = __fdiv_rn(B, det);
  invc[4] = __fdiv_rn(f_sub(f_mul(a,i), f_mul(c,g)), det);
  invc[5] = __fdiv_rn(f_sub(f_mul(c,d), f_mul(a,f)), det);
  invc[6] = __fdiv_rn(C, det);
  invc[7] = __fdiv_rn(f_sub(f_mul(b,g), f_mul(a,h)), det);
  invc[8] = __fdiv_rn(f_sub(f_mul(a,e), f_mul(b,d)), det);
}

// Stage wrapped coords + wrap offsets for molecule b into LDS (exact ref chain).
__device__ __forceinline__ void stage_wrapped(
    const float* __restrict__ coords, int b,
    const float* cl, const float* invc,
    float* wx, float* wy, float* wz, int* wox, int* woy, int* woz)
{
  const float3* __restrict__ c3 = (const float3*)(coords + b*NA*3);
  for (int i = threadIdx.x; i < NA; i += 512) {
    const float3 c = c3[i];
    float p0 = f_add(f_add(f_mul(c.x, invc[0]), f_mul(c.y, invc[3])), f_mul(c.z, invc[6]));
    float p1 = f_add(f_add(f_mul(c.x, invc[1]), f_mul(c.y, invc[4])), f_mul(c.z, invc[7]));
    float p2 = f_add(f_add(f_mul(c.x, invc[2]), f_mul(c.y, invc[5])), f_mul(c.z, invc[8]));
    float fl0 = floorf(p0), fl1 = floorf(p1), fl2 = floorf(p2);
    wox[i] = (int)fl0; woy[i] = (int)fl1; woz[i] = (int)fl2;
    float fr0 = f_sub(p0, fl0), fr1 = f_sub(p1, fl1), fr2 = f_sub(p2, fl2);
    wx[i] = f_add(f_add(f_mul(fr0, cl[0]), f_mul(fr1, cl[3])), f_mul(fr2, cl[6]));
    wy[i] = f_add(f_add(f_mul(fr0, cl[1]), f_mul(fr1, cl[4])), f_mul(fr2, cl[7]));
    wz[i] = f_add(f_add(f_mul(fr0, cl[2]), f_mul(fr1, cl[5])), f_mul(fr2, cl[8]));
  }
}

// Nearest-image select: k = rint(d0/L) in {-1,0,1}; P = -L*k exact; oi = -k.
#define SELECT_P(d0, negLd, invLd, P, oi) \
  { const float kk = __builtin_rintf(f_mul(d0, invLd)); \
    P = f_mul(kk, negLd); oi = -(int)kk; }

__global__ __launch_bounds__(512) void count_k(
    const float* __restrict__ coords, const float* __restrict__ cell,
    int* __restrict__ ws)
{
  const int bid = blockIdx.x;
  const int b = bid / BPM;
  const int blkm = bid % BPM;
  __shared__ float wx[NA], wy[NA], wz[NA];
  __shared__ int wox[NA], woy[NA], woz[NA];
  __shared__ float cl[9], invc[9];
  __shared__ int cw[WPB*27];
  __shared__ int wmax[WPB];
  const int t = threadIdx.x;
  const int w = t >> 6, lane = t & 63;
  if (t < 9) cl[t] = cell[b*9 + t];
  if (t < WPB*27) cw[t] = 0;
  __syncthreads();
  if (t == 0) make_inv(cl, invc);
  __syncthreads();
  stage_wrapped(coords, b, cl, invc, wx, wy, wz, wox, woy, woz);
  __syncthreads();

  const float nLx = -cl[0], nLy = -cl[4], nLz = -cl[8];
  const float iLx = __frcp_rn(cl[0]), iLy = __frcp_rn(cl[4]), iLz = __frcp_rn(cl[8]);
  const int i = blkm*WPB + w;
  const float wxi = wx[i], wyi = wy[i], wzi = wz[i];
  const int woxi = wox[i], woyi = woy[i], wozi = woz[i];

  int mx = 0;
  #pragma unroll
  for (int jb = 0; jb < 6; ++jb) {
    const int j = jb*64 + lane;
    const float d0x = f_sub(wxi, wx[j]);
    const float d0y = f_sub(wyi, wy[j]);
    const float d0z = f_sub(wzi, wz[j]);
    float Px, Py, Pz; int ox, oy, oz;
    SELECT_P(d0x, nLx, iLx, Px, ox);
    SELECT_P(d0y, nLy, iLy, Py, oy);
    SELECT_P(d0z, nLz, iLz, Pz, oz);
    const float dx = f_add(d0x, Px);
    const float dy = f_add(d0y, Py);
    const float dz = f_add(d0z, Pz);
    const float s = f_add(f_add(f_mul(dx,dx), f_mul(dy,dy)), f_mul(dz,dz));
    const float dist = __fsqrt_rn(s);
    const int oidx = 13 + 9*ox + 3*oy + oz;
    const bool valid = (dist < CUT) && (oidx != 13 || i != j);
    if (valid) {
      atomicAdd(&cw[w*27 + oidx], 1);
      const int o0 = ox - (woxi - wox[j]);
      const int o1 = oy - (woyi - woy[j]);
      const int o2 = oz - (wozi - woz[j]);
      int am = abs(o0); am = max(am, abs(o1)); am = max(am, abs(o2));
      mx = max(mx, am);
    }
  }
  #pragma unroll
  for (int d = 32; d > 0; d >>= 1) mx = max(mx, __shfl_down(mx, d));
  if (lane == 0) wmax[w] = mx;
  __syncthreads();
  // per-(o,w) counts, coalesced:  WCNT[bid*216 + o*8 + w]
  if (t < 216) ws[WS_WCNT + bid*216 + t] = cw[(t & 7)*27 + (t >> 3)];
  // per-(b,o) block partial:      PB[(b*27+o)*48 + blkm]
  if (t < 27) {
    int s = 0;
    #pragma unroll
    for (int q = 0; q < WPB; ++q) s += cw[q*27 + t];
    ws[WS_PB + (b*27 + t)*48 + blkm] = s;
  }
  if (t == 0) {
    int m = 0;
    #pragma unroll
    for (int q = 0; q < WPB; ++q) m = max(m, wmax[q]);
    ws[WS_BMAX + bid] = m;
  }
}

__global__ __launch_bounds__(512) void write_k(
    const float* __restrict__ coords, const float* __restrict__ cell,
    const int* __restrict__ ira, const int* __restrict__ ws,
    float* __restrict__ out)
{
  const int bid = blockIdx.x;
  const int b = bid / BPM;
  const int blkm = bid % BPM;
  __shared__ float wx[NA], wy[NA], wz[NA];
  __shared__ int wox[NA], woy[NA], woz[NA];
  __shared__ float cx[NA], cy[NA], cz[NA];
  __shared__ int ira_s[NA];
  __shared__ float cl[9], invc[9];
  __shared__ int cw[WPB*27];               // cursors
  __shared__ int pbl[NB == 16 ? 1296 : 1296]; // PB slice of own b: [27][48]
  __shared__ int wl[216];                  // own block's per-(o,w) counts
  __shared__ int ssh[512], msh[512], exc[432], sbl[27];
  const int t = threadIdx.x;
  const int w = t >> 6, lane = t & 63;

  // ---- prologue loads ----
  if (t < 9) cl[t] = cell[b*9 + t];
  int s1 = 0;
  if (t < 432) {                           // S1[b,o] = sum of 48 block partials
    const int4* p4 = (const int4*)(ws + WS_PB + t*48);
    #pragma unroll
    for (int q = 0; q < 12; ++q) { const int4 v = p4[q]; s1 += v.x + v.y + v.z + v.w; }
  }
  ssh[t] = s1;
  {
    int m = ws[WS_BMAX + t];
    if (t < NBLKS - 512) m = max(m, ws[WS_BMAX + 512 + t]);
    msh[t] = m;
  }
  for (int q = t; q < 1296; q += 512) pbl[q] = ws[WS_PB + b*1296 + q];
  if (t < 216) wl[t] = ws[WS_WCNT + bid*216 + t];
  __syncthreads();
  if (t == 0) make_inv(cl, invc);
  __syncthreads();

  // stage molecule (uses invc)
  stage_wrapped(coords, b, cl, invc, wx, wy, wz, wox, woy, woz);
  {
    const float3* __restrict__ c3 = (const float3*)(coords + b*NA*3);
    for (int i = t; i < NA; i += 512) {
      const float3 c = c3[i];
      cx[i] = c.x; cy[i] = c.y; cz[i] = c.z;
      ira_s[i] = ira[b*NA + i];
    }
  }

  // Hillis-Steele inclusive scan of ssh (512), interleaved after staging
  for (int d = 1; d < 512; d <<= 1) {
    const int v = ssh[t];
    const int add = (t >= d) ? ssh[t - d] : 0;
    __syncthreads();
    ssh[t] = v + add;
    __syncthreads();
  }
  for (int d = 256; d > 0; d >>= 1) {
    if (t < d) msh[t] = max(msh[t], msh[t + d]);
    __syncthreads();
  }
  if (t < 432) exc[t] = ssh[t] - s1;       // exclusive (b,o)-stream starts
  if (t < 27) {                            // SB[o]: preceding blocks of this (b,o)
    int s = 0;
    for (int q = 0; q < blkm; ++q) s += pbl[t*48 + q];
    sbl[t] = s;
  }
  __syncthreads();
  const int mi = msh[0];
  const int nf = 2*mi + 1;
  int total = ssh[431]; if (total > MAXP) total = MAXP;
  // cursors per (o,w): stream start + block prefix + wave prefix
  if (t < 216) {
    const int o = t >> 3, ww = t & 7;
    int s = exc[b*27 + o] + sbl[o];
    for (int q = 0; q < ww; ++q) s += wl[o*8 + q];
    cw[ww*27 + o] = s;
  }
  __syncthreads();

  // ---- ordered compaction ----
  const float nLx = -cl[0], nLy = -cl[4], nLz = -cl[8];
  const float iLx = __frcp_rn(cl[0]), iLy = __frcp_rn(cl[4]), iLz = __frcp_rn(cl[8]);
  const int i = blkm*WPB + w;
  const float wxi = wx[i], wyi = wy[i], wzi = wz[i];
  const int woxi = wox[i], woyi = woy[i], wozi = woz[i];
  const float cxi = cx[i], cyi = cy[i], czi = cz[i];
  const int pfi = ira_s[i];

  #pragma unroll
  for (int jb = 0; jb < 6; ++jb) {
    const int j = jb*64 + lane;
    const float d0x = f_sub(wxi, wx[j]);
    const float d0y = f_sub(wyi, wy[j]);
    const float d0z = f_sub(wzi, wz[j]);
    float Px, Py, Pz; int ox, oy, oz;
    SELECT_P(d0x, nLx, iLx, Px, ox);
    SELECT_P(d0y, nLy, iLy, Py, oy);
    SELECT_P(d0z, nLz, iLz, Pz, oz);
    const float dx = f_add(d0x, Px);
    const float dy = f_add(d0y, Py);
    const float dz = f_add(d0z, Pz);
    const float s = f_add(f_add(f_mul(dx,dx), f_mul(dy,dy)), f_mul(dz,dz));
    const float dist = __fsqrt_rn(s);
    const int oidx = 13 + 9*ox + 3*oy + oz;
    const bool valid = (dist < CUT) && (oidx != 13 || i != j);
    const unsigned long long vm = __ballot(valid);
    unsigned long long same = vm;
    #pragma unroll
    for (int k = 0; k < 5; ++k) {
      const unsigned long long bk = __ballot((oidx >> k) & 1);
      same &= ((oidx >> k) & 1) ? bk : ~bk;
    }
    if (valid) {
      const unsigned long long lower = (1ull << lane) - 1ull;
      const int rank = __popcll(same & lower);
      const int bse = cw[w*27 + oidx];
      if ((same & lower) == 0ull)
        cw[w*27 + oidx] = bse + __popcll(same);
      const int p = bse + rank;
      if (p < MAXP) {
        const int o0 = ox - (woxi - wox[j]);
        const int o1 = oy - (woyi - woy[j]);
        const int o2 = oz - (wozi - woz[j]);
        const float g0 = (float)o0, g1 = (float)o1, g2 = (float)o2;
        const float qx = f_add(f_add(f_mul(g0, cl[0]), f_mul(g1, cl[3])), f_mul(g2, cl[6]));
        const float qy = f_add(f_add(f_mul(g0, cl[1]), f_mul(g1, cl[4])), f_mul(g2, cl[7]));
        const float qz = f_add(f_add(f_mul(g0, cl[2]), f_mul(g1, cl[5])), f_mul(g2, cl[8]));
        const float ax = f_add(f_sub(cxi, cx[j]), qx);
        const float ay = f_add(f_sub(cyi, cy[j]), qy);
        const float az = f_add(f_sub(czi, cz[j]), qz);
        const float s2 = f_add(f_add(f_mul(ax,ax), f_mul(ay,ay)), f_mul(az,az));
        const float dd = __fsqrt_rn(s2);
        out[p]          = dd;
        out[MAXP + p]   = (float)pfi;
        out[2*MAXP + p] = (float)ira_s[j];
        out[3*MAXP + 3*p + 0] = ax;
        out[3*MAXP + 3*p + 1] = ay;
        out[3*MAXP + 3*p + 2] = az;
        out[6*MAXP + 3*p + 0] = g0;
        out[6*MAXP + 3*p + 1] = g1;
        out[6*MAXP + 3*p + 2] = g2;
        out[9*MAXP + p] = (float)((o2+mi) + nf*((o1+mi) + nf*(o0+mi)));
      }
    }
  }

  // Tail fill: slots [total, MAXP) -> zeros except offset_index pad value.
  const float oidx_pad = (float)(mi*(1 + nf + nf*nf));
  const int gtid = bid*512 + t;
  for (int p = total + gtid; p < MAXP; p += NBLKS*512) {
    out[p] = 0.0f;
    out[MAXP + p] = 0.0f;
    out[2*MAXP + p] = 0.0f;
    out[3*MAXP + 3*p + 0] = 0.0f;
    out[3*MAXP + 3*p + 1] = 0.0f;
    out[3*MAXP + 3*p + 2] = 0.0f;
    out[6*MAXP + 3*p + 0] = 0.0f;
    out[6*MAXP + 3*p + 1] = 0.0f;
    out[6*MAXP + 3*p + 2] = 0.0f;
    out[9*MAXP + p] = oidx_pad;
  }
}

extern "C" void kernel_launch(void* const* d_in, const int* in_sizes, int n_in,
                              void* d_out, int out_size, void* d_ws, size_t ws_size,
                              hipStream_t stream) {
  const float* coords = (const float*)d_in[0];   // [16,384,3] f32
  const int*   ira    = (const int*)d_in[3];     // inv_real_atoms [6144]
  const float* cell   = (const float*)d_in[4];   // [16,3,3] f32
  int* ws = (int*)d_ws;
  float* out = (float*)d_out;

  count_k<<<NBLKS, 512, 0, stream>>>(coords, cell, ws);
  write_k<<<NBLKS, 512, 0, stream>>>(coords, cell, ira, ws, out);
}